// Round 1
// baseline (6021.289 us; speedup 1.0000x reference)
//
#include <hip/hip_runtime.h>
#include <stdint.h>

#define B_    4096
#define H_    1024
#define T_    60
#define IN_   1028
#define KA_   1056      // IN_ padded to multiple of 32
#define G4_   4096      // 4*H
#define MLPH_ 64

typedef __attribute__((ext_vector_type(8))) short bf16x8;
typedef __attribute__((ext_vector_type(4))) float f32x4;

#define GLOBAL_AS __attribute__((address_space(1)))
#define LDS_AS    __attribute__((address_space(3)))

__device__ __forceinline__ void gload_lds16(const void* g, void* l) {
  __builtin_amdgcn_global_load_lds((GLOBAL_AS void*)const_cast<void*>(g),
                                   (LDS_AS void*)l, 16, 0, 0);
}

__device__ __forceinline__ unsigned short f2bf(float f) {
  union { float f; unsigned int u; } v; v.f = f;
  unsigned int r = v.u + 0x7FFFu + ((v.u >> 16) & 1u);
  return (unsigned short)(r >> 16);
}

__device__ __forceinline__ float sigmf(float x) {
  float e = __expf(-x);
  return __builtin_amdgcn_rcpf(1.0f + e);
}

__device__ __forceinline__ float tanh_fast(float x) {
  x = fminf(fmaxf(x, -15.0f), 15.0f);
  float e = __expf(2.0f * x);
  return (e - 1.0f) * __builtin_amdgcn_rcpf(e + 1.0f);
}

// ---------------- conversion / setup kernels ----------------

__global__ void k_conv_bf16(const float* __restrict__ src,
                            unsigned short* __restrict__ dst, int n) {
  int i = blockIdx.x * blockDim.x + threadIdx.x;
  int stride = gridDim.x * blockDim.x;
  for (; i < n; i += stride) dst[i] = f2bf(src[i]);
}

// W_ih (4096 x 1028) -> bf16 padded (4096 x 1056)
__global__ void k_conv_wih(const float* __restrict__ w,
                           unsigned short* __restrict__ dst) {
  int i = blockIdx.x * blockDim.x + threadIdx.x;
  int stride = gridDim.x * blockDim.x;
  const int n = G4_ * KA_;
  for (; i < n; i += stride) {
    int r = i / KA_, k = i - r * KA_;
    dst[i] = (k < IN_) ? f2bf(w[(size_t)r * IN_ + k]) : (unsigned short)0;
  }
}

// z_aug = [z | last_pos | last_vel | zero-pad]  (4096 x 1056 bf16)
__global__ void k_build_zaug(const float* __restrict__ z,
                             const float* __restrict__ lp,
                             const float* __restrict__ lv,
                             unsigned short* __restrict__ dst) {
  int i = blockIdx.x * blockDim.x + threadIdx.x;
  int stride = gridDim.x * blockDim.x;
  const int n = B_ * KA_;
  for (; i < n; i += stride) {
    int b = i / KA_, k = i - b * KA_;
    float v;
    if (k < H_)            v = z[(size_t)b * H_ + k];
    else if (k < H_ + 2)   v = lp[b * 2 + (k - H_)];
    else if (k < IN_)      v = lv[b * 2 + (k - H_ - 2)];
    else                   v = 0.0f;
    dst[i] = f2bf(v);
  }
}

// ---------------- x_gates GEMM: (4096 x 1056) @ (1056 x 4096) + b_ih + b_hh ----------------
// block: 128 rows x 256 gate-cols, 4 waves (2x2), each wave 64x128 (4x8 frags)

__global__ __launch_bounds__(256) void k_xgates(
    const unsigned short* __restrict__ zaug, const unsigned short* __restrict__ wih,
    const float* __restrict__ bih, const float* __restrict__ bhh,
    float* __restrict__ xg) {
  __shared__ unsigned short As[128 * 32];
  __shared__ unsigned short Bs[256 * 32];
  const int tid = threadIdx.x, lane = tid & 63, wave = tid >> 6;
  const int bx = blockIdx.x, by = blockIdx.y;
  const int wm = wave >> 1, wn = wave & 1;
  const int r_sub = lane >> 2;          // 0..15 row within 16-row chunk
  const int c16 = (lane & 3) * 16;      // byte offset within 64B row

  f32x4 acc[4][8];
#pragma unroll
  for (int m = 0; m < 4; ++m)
#pragma unroll
    for (int n = 0; n < 8; ++n) acc[m][n] = {0.f, 0.f, 0.f, 0.f};

  for (int kk = 0; kk < KA_ / 32; ++kk) {
    const int k0 = kk * 32;
    __syncthreads();
#pragma unroll
    for (int i = 0; i < 2; ++i) {           // A: 8 chunks of 16 rows
      int ch = wave * 2 + i;
      int row = bx * 128 + ch * 16 + r_sub;
      gload_lds16((const char*)zaug + ((size_t)row * KA_ + k0) * 2 + c16,
                  (char*)As + ch * 1024);
    }
#pragma unroll
    for (int i = 0; i < 4; ++i) {           // B: 16 chunks of 16 gate-rows
      int ch = wave * 4 + i;
      int grow = by * 256 + ch * 16 + r_sub;
      gload_lds16((const char*)wih + ((size_t)grow * KA_ + k0) * 2 + c16,
                  (char*)Bs + ch * 1024);
    }
    __syncthreads();
    bf16x8 a[4], b[8];
#pragma unroll
    for (int m = 0; m < 4; ++m)
      a[m] = *(const bf16x8*)&As[(wm * 64 + m * 16 + (lane & 15)) * 32 + (lane >> 4) * 8];
#pragma unroll
    for (int n = 0; n < 8; ++n)
      b[n] = *(const bf16x8*)&Bs[(wn * 128 + n * 16 + (lane & 15)) * 32 + (lane >> 4) * 8];
#pragma unroll
    for (int m = 0; m < 4; ++m)
#pragma unroll
      for (int n = 0; n < 8; ++n)
        acc[m][n] = __builtin_amdgcn_mfma_f32_16x16x32_bf16(a[m], b[n], acc[m][n], 0, 0, 0);
  }

  const int r0 = (lane >> 4) * 4, cl = lane & 15;
#pragma unroll
  for (int m = 0; m < 4; ++m)
#pragma unroll
    for (int n = 0; n < 8; ++n)
#pragma unroll
      for (int j = 0; j < 4; ++j) {
        int row = bx * 128 + wm * 64 + m * 16 + r0 + j;
        int col = by * 256 + wn * 128 + n * 16 + cl;
        xg[(size_t)row * G4_ + col] = acc[m][n][j] + bih[col] + bhh[col];
      }
}

// ---------------- LSTM step: gates = xg + h @ W_hh^T, fused cell update ----------------
// block: 128 rows x 64 h-cols (x4 gates = 256 gate-cols), 4 waves (2x2),
// each wave 64 rows x 32 h-cols x 4 gates. Lane holds all 4 gates of its element.

__global__ __launch_bounds__(256) void k_step(
    const unsigned short* __restrict__ hprev, const unsigned short* __restrict__ whh,
    const float* __restrict__ xg, float* __restrict__ cbuf,
    unsigned short* __restrict__ hout) {
  __shared__ unsigned short As[128 * 32];
  __shared__ unsigned short Bs[256 * 32];
  const int tid = threadIdx.x, lane = tid & 63, wave = tid >> 6;
  const int bx = blockIdx.x, by = blockIdx.y;
  const int wm = wave >> 1, wn = wave & 1;
  const int r_sub = lane >> 2;
  const int c16 = (lane & 3) * 16;

  f32x4 acc[4][8];   // [m][g*2+n]
#pragma unroll
  for (int m = 0; m < 4; ++m)
#pragma unroll
    for (int n = 0; n < 8; ++n) acc[m][n] = {0.f, 0.f, 0.f, 0.f};

  for (int kk = 0; kk < H_ / 32; ++kk) {
    const int k0 = kk * 32;
    __syncthreads();
#pragma unroll
    for (int i = 0; i < 2; ++i) {           // A: h tile 128x32
      int ch = wave * 2 + i;
      int row = bx * 128 + ch * 16 + r_sub;
      gload_lds16((const char*)hprev + ((size_t)row * H_ + k0) * 2 + c16,
                  (char*)As + ch * 1024);
    }
#pragma unroll
    for (int i = 0; i < 4; ++i) {           // B: W_hh rows for 4 gates x 64 cols
      int ch = wave * 4 + i;
      int g = ch >> 2;
      int jj = (ch & 3) * 16 + r_sub;
      int wrow = g * H_ + by * 64 + jj;
      gload_lds16((const char*)whh + ((size_t)wrow * H_ + k0) * 2 + c16,
                  (char*)Bs + ch * 1024);
    }
    __syncthreads();
    bf16x8 a[4], b[8];
#pragma unroll
    for (int m = 0; m < 4; ++m)
      a[m] = *(const bf16x8*)&As[(wm * 64 + m * 16 + (lane & 15)) * 32 + (lane >> 4) * 8];
#pragma unroll
    for (int g = 0; g < 4; ++g)
#pragma unroll
      for (int n = 0; n < 2; ++n)
        b[g * 2 + n] = *(const bf16x8*)&Bs[(g * 64 + wn * 32 + n * 16 + (lane & 15)) * 32 + (lane >> 4) * 8];
#pragma unroll
    for (int m = 0; m < 4; ++m)
#pragma unroll
      for (int q = 0; q < 8; ++q)
        acc[m][q] = __builtin_amdgcn_mfma_f32_16x16x32_bf16(a[m], b[q], acc[m][q], 0, 0, 0);
  }

  const int r0 = (lane >> 4) * 4, cl = lane & 15;
#pragma unroll
  for (int m = 0; m < 4; ++m)
#pragma unroll
    for (int n = 0; n < 2; ++n)
#pragma unroll
      for (int j = 0; j < 4; ++j) {
        int row = bx * 128 + wm * 64 + m * 16 + r0 + j;   // batch index
        int hc = by * 64 + wn * 32 + n * 16 + cl;         // h column
        size_t xb = (size_t)row * G4_;
        float iv = sigmf(acc[m][0 + n][j] + xg[xb + hc]);
        float fv = sigmf(acc[m][2 + n][j] + xg[xb + 1024 + hc]);
        float gv = tanh_fast(acc[m][4 + n][j] + xg[xb + 2048 + hc]);
        float ov = sigmf(acc[m][6 + n][j] + xg[xb + 3072 + hc]);
        size_t ci = (size_t)row * H_ + hc;
        float cv = fv * cbuf[ci] + iv * gv;
        cbuf[ci] = cv;
        hout[ci] = f2bf(ov * tanh_fast(cv));
      }
}

// ---------------- MLP: delta[:,t,:] = relu(h @ W1^T + b1) @ W2^T + b2 ----------------
// block: 64 rows, 4 waves; wave w computes rows [w*16, w*16+16) x 64 hidden

__global__ __launch_bounds__(256) void k_mlp(
    const unsigned short* __restrict__ h, const unsigned short* __restrict__ w1,
    const float* __restrict__ b1, const float* __restrict__ w2,
    const float* __restrict__ b2, float* __restrict__ delta, int t) {
  __shared__ unsigned short As[64 * 32];
  __shared__ unsigned short Bs[64 * 32];
  __shared__ float hid[64][65];
  const int tid = threadIdx.x, lane = tid & 63, wave = tid >> 6;
  const int bx = blockIdx.x;
  const int r_sub = lane >> 2;
  const int c16 = (lane & 3) * 16;

  f32x4 acc[4];
#pragma unroll
  for (int n = 0; n < 4; ++n) acc[n] = {0.f, 0.f, 0.f, 0.f};

  for (int kk = 0; kk < H_ / 32; ++kk) {
    const int k0 = kk * 32;
    __syncthreads();
    {
      int row = bx * 64 + wave * 16 + r_sub;
      gload_lds16((const char*)h + ((size_t)row * H_ + k0) * 2 + c16,
                  (char*)As + wave * 1024);
    }
    {
      int jj = wave * 16 + r_sub;
      gload_lds16((const char*)w1 + ((size_t)jj * H_ + k0) * 2 + c16,
                  (char*)Bs + wave * 1024);
    }
    __syncthreads();
    bf16x8 a = *(const bf16x8*)&As[(wave * 16 + (lane & 15)) * 32 + (lane >> 4) * 8];
#pragma unroll
    for (int n = 0; n < 4; ++n) {
      bf16x8 b = *(const bf16x8*)&Bs[(n * 16 + (lane & 15)) * 32 + (lane >> 4) * 8];
      acc[n] = __builtin_amdgcn_mfma_f32_16x16x32_bf16(a, b, acc[n], 0, 0, 0);
    }
  }

  const int r0 = (lane >> 4) * 4, cl = lane & 15;
#pragma unroll
  for (int n = 0; n < 4; ++n)
#pragma unroll
    for (int j = 0; j < 4; ++j) {
      int row = wave * 16 + r0 + j;     // local row 0..63
      int col = n * 16 + cl;            // hidden unit 0..63
      hid[row][col] = fmaxf(acc[n][j] + b1[col], 0.0f);
    }
  __syncthreads();

  if (tid < 128) {
    int r = tid >> 1, d = tid & 1;
    float s = b2[d];
#pragma unroll 8
    for (int k2 = 0; k2 < 64; ++k2) s += hid[r][k2] * w2[d * 64 + k2];
    delta[((size_t)(bx * 64 + r) * T_ + t) * 2 + d] = s;
  }
}

// ---------------- final cumsum over T + last_pos ----------------

__global__ void k_cumsum(const float* __restrict__ delta,
                         const float* __restrict__ lp, float* __restrict__ out) {
  int id = blockIdx.x * blockDim.x + threadIdx.x;
  if (id >= B_ * 2) return;
  int b = id >> 1, d = id & 1;
  float cum = lp[b * 2 + d];
  size_t base = (size_t)b * T_ * 2 + d;
  for (int t = 0; t < T_; ++t) {
    cum += delta[base + t * 2];
    out[base + t * 2] = cum;
  }
}

// ---------------- launch ----------------

extern "C" void kernel_launch(void* const* d_in, const int* in_sizes, int n_in,
                              void* d_out, int out_size, void* d_ws, size_t ws_size,
                              hipStream_t stream) {
  const float* z   = (const float*)d_in[0];
  const float* lv  = (const float*)d_in[1];
  const float* lp  = (const float*)d_in[2];
  const float* Wih = (const float*)d_in[3];
  const float* Whh = (const float*)d_in[4];
  const float* bih = (const float*)d_in[5];
  const float* bhh = (const float*)d_in[6];
  const float* W1  = (const float*)d_in[7];
  const float* b1  = (const float*)d_in[8];
  const float* W2  = (const float*)d_in[9];
  const float* b2  = (const float*)d_in[10];
  float* out = (float*)d_out;

  char* ws = (char*)d_ws;
  float*          xg     = (float*)(ws + 0);                 //  67108864 B
  unsigned short* whh_bf = (unsigned short*)(ws + 67108864); //   8388608 B
  unsigned short* wih_bf = (unsigned short*)(ws + 75497472); //   8650752 B
  unsigned short* zaug   = (unsigned short*)(ws + 84148224); //   8650752 B
  unsigned short* w1_bf  = (unsigned short*)(ws + 92798976); //    131072 B
  unsigned short* h_a    = (unsigned short*)(ws + 92930048); //   8388608 B
  unsigned short* h_b    = (unsigned short*)(ws + 101318656);//   8388608 B
  float*          cbuf   = (float*)(ws + 109707264);         //  16777216 B
  float*          delta  = (float*)(ws + 126484480);         //   1966080 B  -> total ~128.5 MB

  hipMemsetAsync(h_a, 0, (size_t)B_ * H_ * 2, stream);
  hipMemsetAsync(cbuf, 0, (size_t)B_ * H_ * 4, stream);

  k_conv_bf16 <<<2048, 256, 0, stream>>>(Whh, whh_bf, G4_ * H_);
  k_conv_wih  <<<2048, 256, 0, stream>>>(Wih, wih_bf);
  k_build_zaug<<<2048, 256, 0, stream>>>(z, lp, lv, zaug);
  k_conv_bf16 <<<256, 256, 0, stream>>>(W1, w1_bf, MLPH_ * H_);

  k_xgates<<<dim3(32, 16), 256, 0, stream>>>(zaug, wih_bf, bih, bhh, xg);

  const unsigned short* hp = h_a;
  unsigned short*       hc = h_b;
  for (int t = 0; t < T_; ++t) {
    k_step<<<dim3(32, 16), 256, 0, stream>>>(hp, whh_bf, xg, cbuf, hc);
    k_mlp <<<64, 256, 0, stream>>>(hc, w1_bf, b1, W2, b2, delta, t);
    const unsigned short* tmp = hc;
    hc = (unsigned short*)hp;
    hp = tmp;
  }

  k_cumsum<<<32, 256, 0, stream>>>(delta, lp, out);
}

// Round 2
// 3540.497 us; speedup vs baseline: 1.7007x; 1.7007x over previous
//
#include <hip/hip_runtime.h>
#include <stdint.h>

#define B_    4096
#define H_    1024
#define T_    60
#define IN_   1028
#define KA_   1056      // IN_ padded to multiple of 32
#define G4_   4096      // 4*H
#define MLPH_ 64
#define NB_   6         // MLP batch depth / h ring size

typedef __attribute__((ext_vector_type(8))) short bf16x8;
typedef __attribute__((ext_vector_type(4))) float f32x4;
typedef __attribute__((ext_vector_type(4))) unsigned short u16x4;

#define GLOBAL_AS __attribute__((address_space(1)))
#define LDS_AS    __attribute__((address_space(3)))

__device__ __forceinline__ void gload_lds16(const void* g, void* l) {
  __builtin_amdgcn_global_load_lds((GLOBAL_AS void*)const_cast<void*>(g),
                                   (LDS_AS void*)l, 16, 0, 0);
}

__device__ __forceinline__ unsigned short f2bf(float f) {
  union { float f; unsigned int u; } v; v.f = f;
  unsigned int r = v.u + 0x7FFFu + ((v.u >> 16) & 1u);
  return (unsigned short)(r >> 16);
}

__device__ __forceinline__ float bf2f(unsigned short u) {
  union { unsigned int u; float f; } v; v.u = ((unsigned int)u) << 16;
  return v.f;
}

__device__ __forceinline__ float sigmf(float x) {
  float e = __expf(-x);
  return __builtin_amdgcn_rcpf(1.0f + e);
}

__device__ __forceinline__ float tanh_fast(float x) {
  x = fminf(fmaxf(x, -15.0f), 15.0f);
  float e = __expf(2.0f * x);
  return (e - 1.0f) * __builtin_amdgcn_rcpf(e + 1.0f);
}

// ---------------- conversion / setup kernels ----------------

__global__ void k_conv_bf16(const float* __restrict__ src,
                            unsigned short* __restrict__ dst, int n) {
  int i = blockIdx.x * blockDim.x + threadIdx.x;
  int stride = gridDim.x * blockDim.x;
  for (; i < n; i += stride) dst[i] = f2bf(src[i]);
}

// W_ih (4096 x 1028) -> bf16 padded (4096 x 1056)
__global__ void k_conv_wih(const float* __restrict__ w,
                           unsigned short* __restrict__ dst) {
  int i = blockIdx.x * blockDim.x + threadIdx.x;
  int stride = gridDim.x * blockDim.x;
  const int n = G4_ * KA_;
  for (; i < n; i += stride) {
    int r = i / KA_, k = i - r * KA_;
    dst[i] = (k < IN_) ? f2bf(w[(size_t)r * IN_ + k]) : (unsigned short)0;
  }
}

// z_aug = [z | last_pos | last_vel | zero-pad]  (4096 x 1056 bf16)
__global__ void k_build_zaug(const float* __restrict__ z,
                             const float* __restrict__ lp,
                             const float* __restrict__ lv,
                             unsigned short* __restrict__ dst) {
  int i = blockIdx.x * blockDim.x + threadIdx.x;
  int stride = gridDim.x * blockDim.x;
  const int n = B_ * KA_;
  for (; i < n; i += stride) {
    int b = i / KA_, k = i - b * KA_;
    float v;
    if (k < H_)            v = z[(size_t)b * H_ + k];
    else if (k < H_ + 2)   v = lp[b * 2 + (k - H_)];
    else if (k < IN_)      v = lv[b * 2 + (k - H_ - 2)];
    else                   v = 0.0f;
    dst[i] = f2bf(v);
  }
}

// ---------------- x_gates GEMM -> interleaved bf16x4 per (b, hc) ----------------
// block 128 rows x (32 h-cols x 4 gates); 4 waves of 32 rows x 128 cols;
// grid (32, 32) = 1024 blocks -> 3 blocks/CU

__global__ __launch_bounds__(256, 3) void k_xgates(
    const unsigned short* __restrict__ zaug, const unsigned short* __restrict__ wih,
    const float* __restrict__ bih, const float* __restrict__ bhh,
    u16x4* __restrict__ xg4) {
  __shared__ unsigned short As[128 * 32];
  __shared__ unsigned short Bs[128 * 32];
  const int tid = threadIdx.x, lane = tid & 63, wave = tid >> 6;
  const int bx = blockIdx.x, by = blockIdx.y;
  const int r_sub = lane >> 2;          // 0..15
  const int c16 = (lane & 3) * 16;      // byte offset in 64B row

  f32x4 acc[2][8];
#pragma unroll
  for (int m = 0; m < 2; ++m)
#pragma unroll
    for (int n = 0; n < 8; ++n) acc[m][n] = {0.f, 0.f, 0.f, 0.f};

  for (int kk = 0; kk < KA_ / 32; ++kk) {
    const int k0 = kk * 32;
    __syncthreads();
#pragma unroll
    for (int i = 0; i < 2; ++i) {           // A: 8 chunks of 16 rows
      int ch = wave * 2 + i;
      int row = bx * 128 + ch * 16 + r_sub;
      gload_lds16((const char*)zaug + ((size_t)row * KA_ + k0) * 2 + c16,
                  (char*)As + ch * 1024);
    }
#pragma unroll
    for (int i = 0; i < 2; ++i) {           // B: 8 chunks of 16 gate-rows
      int ch = wave * 2 + i;
      int g = ch >> 1;
      int wrow = g * H_ + by * 32 + (ch & 1) * 16 + r_sub;
      gload_lds16((const char*)wih + ((size_t)wrow * KA_ + k0) * 2 + c16,
                  (char*)Bs + ch * 1024);
    }
    __syncthreads();
    bf16x8 a[2], b[8];
#pragma unroll
    for (int m = 0; m < 2; ++m)
      a[m] = *(const bf16x8*)&As[(wave * 32 + m * 16 + (lane & 15)) * 32 + (lane >> 4) * 8];
#pragma unroll
    for (int n = 0; n < 8; ++n)
      b[n] = *(const bf16x8*)&Bs[(n * 16 + (lane & 15)) * 32 + (lane >> 4) * 8];
#pragma unroll
    for (int m = 0; m < 2; ++m)
#pragma unroll
      for (int n = 0; n < 8; ++n)
        acc[m][n] = __builtin_amdgcn_mfma_f32_16x16x32_bf16(a[m], b[n], acc[m][n], 0, 0, 0);
  }

  const int r0 = (lane >> 4) * 4, cl = lane & 15;
#pragma unroll
  for (int m = 0; m < 2; ++m)
#pragma unroll
    for (int j = 0; j < 4; ++j) {
      int row = bx * 128 + wave * 32 + m * 16 + r0 + j;
#pragma unroll
      for (int p = 0; p < 2; ++p) {
        int hc = by * 32 + p * 16 + cl;
        float iv = acc[m][0 + p][j] + bih[hc]        + bhh[hc];
        float fv = acc[m][2 + p][j] + bih[1024 + hc] + bhh[1024 + hc];
        float gv = acc[m][4 + p][j] + bih[2048 + hc] + bhh[2048 + hc];
        float ov = acc[m][6 + p][j] + bih[3072 + hc] + bhh[3072 + hc];
        u16x4 st = {f2bf(iv), f2bf(fv), f2bf(gv), f2bf(ov)};
        xg4[(size_t)row * H_ + hc] = st;
      }
    }
}

// ---------------- LSTM step: gates = xg + h @ W_hh^T, fused cell update ----------------
// same 128 x (32 h-cols x 4 gates) tiling, grid (32, 32)

__global__ __launch_bounds__(256, 3) void k_step(
    const unsigned short* __restrict__ hprev, const unsigned short* __restrict__ whh,
    const u16x4* __restrict__ xg4, float* __restrict__ cbuf,
    unsigned short* __restrict__ hout) {
  __shared__ unsigned short As[128 * 32];
  __shared__ unsigned short Bs[128 * 32];
  const int tid = threadIdx.x, lane = tid & 63, wave = tid >> 6;
  const int bx = blockIdx.x, by = blockIdx.y;
  const int r_sub = lane >> 2;
  const int c16 = (lane & 3) * 16;

  f32x4 acc[2][8];   // [m][g*2+p]
#pragma unroll
  for (int m = 0; m < 2; ++m)
#pragma unroll
    for (int n = 0; n < 8; ++n) acc[m][n] = {0.f, 0.f, 0.f, 0.f};

  for (int kk = 0; kk < H_ / 32; ++kk) {
    const int k0 = kk * 32;
    __syncthreads();
#pragma unroll
    for (int i = 0; i < 2; ++i) {           // A: h tile 128x32
      int ch = wave * 2 + i;
      int row = bx * 128 + ch * 16 + r_sub;
      gload_lds16((const char*)hprev + ((size_t)row * H_ + k0) * 2 + c16,
                  (char*)As + ch * 1024);
    }
#pragma unroll
    for (int i = 0; i < 2; ++i) {           // B: W_hh rows, 4 gates x 32 cols
      int ch = wave * 2 + i;
      int g = ch >> 1;
      int wrow = g * H_ + by * 32 + (ch & 1) * 16 + r_sub;
      gload_lds16((const char*)whh + ((size_t)wrow * H_ + k0) * 2 + c16,
                  (char*)Bs + ch * 1024);
    }
    __syncthreads();
    bf16x8 a[2], b[8];
#pragma unroll
    for (int m = 0; m < 2; ++m)
      a[m] = *(const bf16x8*)&As[(wave * 32 + m * 16 + (lane & 15)) * 32 + (lane >> 4) * 8];
#pragma unroll
    for (int n = 0; n < 8; ++n)
      b[n] = *(const bf16x8*)&Bs[(n * 16 + (lane & 15)) * 32 + (lane >> 4) * 8];
#pragma unroll
    for (int m = 0; m < 2; ++m)
#pragma unroll
      for (int n = 0; n < 8; ++n)
        acc[m][n] = __builtin_amdgcn_mfma_f32_16x16x32_bf16(a[m], b[n], acc[m][n], 0, 0, 0);
  }

  const int r0 = (lane >> 4) * 4, cl = lane & 15;
#pragma unroll
  for (int m = 0; m < 2; ++m)
#pragma unroll
    for (int j = 0; j < 4; ++j) {
      int row = bx * 128 + wave * 32 + m * 16 + r0 + j;   // batch index
#pragma unroll
      for (int p = 0; p < 2; ++p) {
        int hc = by * 32 + p * 16 + cl;                   // h column
        u16x4 xv = xg4[(size_t)row * H_ + hc];
        float iv = sigmf(acc[m][0 + p][j] + bf2f(xv[0]));
        float fv = sigmf(acc[m][2 + p][j] + bf2f(xv[1]));
        float gv = tanh_fast(acc[m][4 + p][j] + bf2f(xv[2]));
        float ov = sigmf(acc[m][6 + p][j] + bf2f(xv[3]));
        size_t ci = (size_t)row * H_ + hc;
        float cv = fv * cbuf[ci] + iv * gv;
        cbuf[ci] = cv;
        hout[ci] = f2bf(ov * tanh_fast(cv));
      }
    }
}

// ---------------- batched MLP over NB_ steps ----------------
// grid (64 row-blocks, NB_ steps); block handles 64 rows x 64 hidden

__global__ __launch_bounds__(256) void k_mlp(
    const unsigned short* __restrict__ hring, const unsigned short* __restrict__ w1,
    const float* __restrict__ b1, const float* __restrict__ w2,
    const float* __restrict__ b2, float* __restrict__ delta, int t0) {
  __shared__ unsigned short As[64 * 32];
  __shared__ unsigned short Bs[64 * 32];
  __shared__ float hid[64][65];
  const int tid = threadIdx.x, lane = tid & 63, wave = tid >> 6;
  const int bx = blockIdx.x;
  const unsigned short* h = hring + (size_t)blockIdx.y * B_ * H_;
  const int t = t0 + blockIdx.y;
  const int r_sub = lane >> 2;
  const int c16 = (lane & 3) * 16;

  f32x4 acc[4];
#pragma unroll
  for (int n = 0; n < 4; ++n) acc[n] = {0.f, 0.f, 0.f, 0.f};

  for (int kk = 0; kk < H_ / 32; ++kk) {
    const int k0 = kk * 32;
    __syncthreads();
    {
      int row = bx * 64 + wave * 16 + r_sub;
      gload_lds16((const char*)h + ((size_t)row * H_ + k0) * 2 + c16,
                  (char*)As + wave * 1024);
    }
    {
      int jj = wave * 16 + r_sub;
      gload_lds16((const char*)w1 + ((size_t)jj * H_ + k0) * 2 + c16,
                  (char*)Bs + wave * 1024);
    }
    __syncthreads();
    bf16x8 a = *(const bf16x8*)&As[(wave * 16 + (lane & 15)) * 32 + (lane >> 4) * 8];
#pragma unroll
    for (int n = 0; n < 4; ++n) {
      bf16x8 b = *(const bf16x8*)&Bs[(n * 16 + (lane & 15)) * 32 + (lane >> 4) * 8];
      acc[n] = __builtin_amdgcn_mfma_f32_16x16x32_bf16(a, b, acc[n], 0, 0, 0);
    }
  }

  const int r0 = (lane >> 4) * 4, cl = lane & 15;
#pragma unroll
  for (int n = 0; n < 4; ++n)
#pragma unroll
    for (int j = 0; j < 4; ++j) {
      int row = wave * 16 + r0 + j;     // local row 0..63
      int col = n * 16 + cl;            // hidden unit 0..63
      hid[row][col] = fmaxf(acc[n][j] + b1[col], 0.0f);
    }
  __syncthreads();

  if (tid < 128) {
    int r = tid >> 1, d = tid & 1;
    float s = b2[d];
#pragma unroll 8
    for (int k2 = 0; k2 < 64; ++k2) s += hid[r][k2] * w2[d * 64 + k2];
    delta[((size_t)(bx * 64 + r) * T_ + t) * 2 + d] = s;
  }
}

// ---------------- final cumsum over T + last_pos ----------------

__global__ void k_cumsum(const float* __restrict__ delta,
                         const float* __restrict__ lp, float* __restrict__ out) {
  int id = blockIdx.x * blockDim.x + threadIdx.x;
  if (id >= B_ * 2) return;
  int b = id >> 1, d = id & 1;
  float cum = lp[b * 2 + d];
  size_t base = (size_t)b * T_ * 2 + d;
  for (int t = 0; t < T_; ++t) {
    cum += delta[base + t * 2];
    out[base + t * 2] = cum;
  }
}

// ---------------- launch ----------------

extern "C" void kernel_launch(void* const* d_in, const int* in_sizes, int n_in,
                              void* d_out, int out_size, void* d_ws, size_t ws_size,
                              hipStream_t stream) {
  const float* z   = (const float*)d_in[0];
  const float* lv  = (const float*)d_in[1];
  const float* lp  = (const float*)d_in[2];
  const float* Wih = (const float*)d_in[3];
  const float* Whh = (const float*)d_in[4];
  const float* bih = (const float*)d_in[5];
  const float* bhh = (const float*)d_in[6];
  const float* W1  = (const float*)d_in[7];
  const float* b1  = (const float*)d_in[8];
  const float* W2  = (const float*)d_in[9];
  const float* b2  = (const float*)d_in[10];
  float* out = (float*)d_out;

  char* ws = (char*)d_ws;
  size_t off = 0;
  u16x4*          xg4    = (u16x4*)(ws + off);          off += (size_t)B_ * H_ * 8;       // 33554432
  unsigned short* whh_bf = (unsigned short*)(ws + off); off += (size_t)G4_ * H_ * 2;      //  8388608
  unsigned short* wih_bf = (unsigned short*)(ws + off); off += (size_t)G4_ * KA_ * 2;     //  8650752
  unsigned short* zaug   = (unsigned short*)(ws + off); off += (size_t)B_ * KA_ * 2;      //  8650752
  unsigned short* w1_bf  = (unsigned short*)(ws + off); off += (size_t)MLPH_ * H_ * 2;    //   131072
  unsigned short* hring  = (unsigned short*)(ws + off); off += (size_t)NB_ * B_ * H_ * 2; // 50331648
  float*          cbuf   = (float*)(ws + off);          off += (size_t)B_ * H_ * 4;       // 16777216
  float*          delta  = (float*)(ws + off);          off += (size_t)B_ * T_ * 2 * 4;   //  1966080
  // total 128450560 bytes

  const size_t BH = (size_t)B_ * H_;

  // zero c and the h(-1) slot (= slot NB_-1 of the ring)
  hipMemsetAsync(hring + (NB_ - 1) * BH, 0, BH * 2, stream);
  hipMemsetAsync(cbuf, 0, BH * 4, stream);

  k_conv_bf16 <<<2048, 256, 0, stream>>>(Whh, whh_bf, G4_ * H_);
  k_conv_wih  <<<2048, 256, 0, stream>>>(Wih, wih_bf);
  k_build_zaug<<<2048, 256, 0, stream>>>(z, lp, lv, zaug);
  k_conv_bf16 <<<256, 256, 0, stream>>>(W1, w1_bf, MLPH_ * H_);

  k_xgates<<<dim3(32, 32), 256, 0, stream>>>(zaug, wih_bf, bih, bhh, xg4);

  for (int t = 0; t < T_; ++t) {
    const unsigned short* hp = hring + (size_t)((t + NB_ - 1) % NB_) * BH;
    unsigned short*       hc = hring + (size_t)(t % NB_) * BH;
    k_step<<<dim3(32, 32), 256, 0, stream>>>(hp, whh_bf, xg4, cbuf, hc);
    if ((t % NB_) == NB_ - 1)
      k_mlp<<<dim3(64, NB_), 256, 0, stream>>>(hring, w1_bf, b1, W2, b2, delta, t - (NB_ - 1));
  }

  k_cumsum<<<32, 256, 0, stream>>>(delta, lp, out);
}

// Round 3
// 2974.302 us; speedup vs baseline: 2.0244x; 1.1904x over previous
//
#include <hip/hip_runtime.h>
#include <stdint.h>

#define B_    4096
#define H_    1024
#define T_    60
#define IN_   1028
#define KA_   1056      // IN_ padded to multiple of 32
#define G4_   4096      // 4*H
#define MLPH_ 64
#define NB_   6         // MLP batch depth / h ring size

typedef __attribute__((ext_vector_type(8))) short bf16x8;
typedef __attribute__((ext_vector_type(4))) float f32x4;
typedef __attribute__((ext_vector_type(4))) unsigned short u16x4;

#define GLOBAL_AS __attribute__((address_space(1)))
#define LDS_AS    __attribute__((address_space(3)))

__device__ __forceinline__ void gload_lds16(const void* g, void* l) {
  __builtin_amdgcn_global_load_lds((GLOBAL_AS void*)const_cast<void*>(g),
                                   (LDS_AS void*)l, 16, 0, 0);
}

__device__ __forceinline__ unsigned short f2bf(float f) {
  union { float f; unsigned int u; } v; v.f = f;
  unsigned int r = v.u + 0x7FFFu + ((v.u >> 16) & 1u);
  return (unsigned short)(r >> 16);
}

__device__ __forceinline__ float bf2f(unsigned short u) {
  union { unsigned int u; float f; } v; v.u = ((unsigned int)u) << 16;
  return v.f;
}

__device__ __forceinline__ float sigmf(float x) {
  float e = __expf(-x);
  return __builtin_amdgcn_rcpf(1.0f + e);
}

__device__ __forceinline__ float tanh_fast(float x) {
  x = fminf(fmaxf(x, -15.0f), 15.0f);
  float e = __expf(2.0f * x);
  return (e - 1.0f) * __builtin_amdgcn_rcpf(e + 1.0f);
}

// ---------------- conversion / setup kernels ----------------

__global__ void k_conv_bf16(const float* __restrict__ src,
                            unsigned short* __restrict__ dst, int n) {
  int i = blockIdx.x * blockDim.x + threadIdx.x;
  int stride = gridDim.x * blockDim.x;
  for (; i < n; i += stride) dst[i] = f2bf(src[i]);
}

// W_ih (4096 x 1028) -> bf16 padded (4096 x 1056)
__global__ void k_conv_wih(const float* __restrict__ w,
                           unsigned short* __restrict__ dst) {
  int i = blockIdx.x * blockDim.x + threadIdx.x;
  int stride = gridDim.x * blockDim.x;
  const int n = G4_ * KA_;
  for (; i < n; i += stride) {
    int r = i / KA_, k = i - r * KA_;
    dst[i] = (k < IN_) ? f2bf(w[(size_t)r * IN_ + k]) : (unsigned short)0;
  }
}

// z_aug = [z | last_pos | last_vel | zero-pad]  (4096 x 1056 bf16)
__global__ void k_build_zaug(const float* __restrict__ z,
                             const float* __restrict__ lp,
                             const float* __restrict__ lv,
                             unsigned short* __restrict__ dst) {
  int i = blockIdx.x * blockDim.x + threadIdx.x;
  int stride = gridDim.x * blockDim.x;
  const int n = B_ * KA_;
  for (; i < n; i += stride) {
    int b = i / KA_, k = i - b * KA_;
    float v;
    if (k < H_)            v = z[(size_t)b * H_ + k];
    else if (k < H_ + 2)   v = lp[b * 2 + (k - H_)];
    else if (k < IN_)      v = lv[b * 2 + (k - H_ - 2)];
    else                   v = 0.0f;
    dst[i] = f2bf(v);
  }
}

// ---------------- x_gates GEMM -> interleaved bf16x4 per (b, hc) ----------------
// 128 rows x (32 hc x 4 gates); waves 2x2: wave = 64 rows x 16 hc x 4 gates.
// Double-buffered LDS, stage-early, one barrier per K-step.

__global__ __launch_bounds__(256, 4) void k_xgates(
    const unsigned short* __restrict__ zaug, const unsigned short* __restrict__ wih,
    const float* __restrict__ bih, const float* __restrict__ bhh,
    u16x4* __restrict__ xg4) {
  __shared__ unsigned short As[2][128 * 32];
  __shared__ unsigned short Bs[2][128 * 32];
  const int tid = threadIdx.x, lane = tid & 63, wave = tid >> 6;
  const int bx = blockIdx.x, by = blockIdx.y;
  const int wm = wave >> 1, wn = wave & 1;
  const int rs = lane >> 2;
  const int c16 = (lane & 3) * 16;

  const char* asrc0 = (const char*)zaug + ((size_t)(bx * 128 + (wave * 2 + 0) * 16 + rs) * KA_) * 2 + c16;
  const char* asrc1 = (const char*)zaug + ((size_t)(bx * 128 + (wave * 2 + 1) * 16 + rs) * KA_) * 2 + c16;
  const char* bsrc0 = (const char*)wih  + ((size_t)(wave * H_ + by * 32 +  0 + rs) * KA_) * 2 + c16;
  const char* bsrc1 = (const char*)wih  + ((size_t)(wave * H_ + by * 32 + 16 + rs) * KA_) * 2 + c16;

  f32x4 acc[4][4];   // [gate][m]
#pragma unroll
  for (int g = 0; g < 4; ++g)
#pragma unroll
    for (int m = 0; m < 4; ++m) acc[g][m] = {0.f, 0.f, 0.f, 0.f};

  // prologue: stage k-tile 0 into buf 0
  gload_lds16(asrc0, &As[0][(wave * 2 + 0) * 512]);
  gload_lds16(asrc1, &As[0][(wave * 2 + 1) * 512]);
  gload_lds16(bsrc0, &Bs[0][(wave * 2 + 0) * 512]);
  gload_lds16(bsrc1, &Bs[0][(wave * 2 + 1) * 512]);
  __syncthreads();

  const int nt = KA_ / 32;
  int cur = 0;
  for (int kk = 0; kk < nt; ++kk) {
    if (kk + 1 < nt) {
      const size_t kb = (size_t)(kk + 1) * 64;
      gload_lds16(asrc0 + kb, &As[cur ^ 1][(wave * 2 + 0) * 512]);
      gload_lds16(asrc1 + kb, &As[cur ^ 1][(wave * 2 + 1) * 512]);
      gload_lds16(bsrc0 + kb, &Bs[cur ^ 1][(wave * 2 + 0) * 512]);
      gload_lds16(bsrc1 + kb, &Bs[cur ^ 1][(wave * 2 + 1) * 512]);
    }
    bf16x8 a[4], b[4];
#pragma unroll
    for (int m = 0; m < 4; ++m)
      a[m] = *(const bf16x8*)&As[cur][(wm * 64 + m * 16 + (lane & 15)) * 32 + (lane >> 4) * 8];
#pragma unroll
    for (int g = 0; g < 4; ++g)
      b[g] = *(const bf16x8*)&Bs[cur][((g * 2 + wn) * 16 + (lane & 15)) * 32 + (lane >> 4) * 8];
#pragma unroll
    for (int g = 0; g < 4; ++g)
#pragma unroll
      for (int m = 0; m < 4; ++m)
        acc[g][m] = __builtin_amdgcn_mfma_f32_16x16x32_bf16(a[m], b[g], acc[g][m], 0, 0, 0);
    __syncthreads();
    cur ^= 1;
  }

  const int r0 = (lane >> 4) * 4, cl = lane & 15;
  const int hc = by * 32 + wn * 16 + cl;
  const float bi = bih[hc]        + bhh[hc];
  const float bf = bih[1024 + hc] + bhh[1024 + hc];
  const float bg = bih[2048 + hc] + bhh[2048 + hc];
  const float bo = bih[3072 + hc] + bhh[3072 + hc];
#pragma unroll
  for (int m = 0; m < 4; ++m)
#pragma unroll
    for (int j = 0; j < 4; ++j) {
      int row = bx * 128 + wm * 64 + m * 16 + r0 + j;
      u16x4 st = {f2bf(acc[0][m][j] + bi), f2bf(acc[1][m][j] + bf),
                  f2bf(acc[2][m][j] + bg), f2bf(acc[3][m][j] + bo)};
      xg4[(size_t)row * H_ + hc] = st;
    }
}

// ---------------- LSTM step: gates = xg + h @ W_hh^T, fused cell update ----------------

__global__ __launch_bounds__(256, 4) void k_step(
    const unsigned short* __restrict__ hprev, const unsigned short* __restrict__ whh,
    const u16x4* __restrict__ xg4, float* __restrict__ cbuf,
    unsigned short* __restrict__ hout) {
  __shared__ unsigned short As[2][128 * 32];
  __shared__ unsigned short Bs[2][128 * 32];
  const int tid = threadIdx.x, lane = tid & 63, wave = tid >> 6;
  const int bx = blockIdx.x, by = blockIdx.y;
  const int wm = wave >> 1, wn = wave & 1;
  const int rs = lane >> 2;
  const int c16 = (lane & 3) * 16;

  const char* asrc0 = (const char*)hprev + ((size_t)(bx * 128 + (wave * 2 + 0) * 16 + rs) * H_) * 2 + c16;
  const char* asrc1 = (const char*)hprev + ((size_t)(bx * 128 + (wave * 2 + 1) * 16 + rs) * H_) * 2 + c16;
  const char* bsrc0 = (const char*)whh   + ((size_t)(wave * H_ + by * 32 +  0 + rs) * H_) * 2 + c16;
  const char* bsrc1 = (const char*)whh   + ((size_t)(wave * H_ + by * 32 + 16 + rs) * H_) * 2 + c16;

  f32x4 acc[4][4];   // [gate][m]
#pragma unroll
  for (int g = 0; g < 4; ++g)
#pragma unroll
    for (int m = 0; m < 4; ++m) acc[g][m] = {0.f, 0.f, 0.f, 0.f};

  gload_lds16(asrc0, &As[0][(wave * 2 + 0) * 512]);
  gload_lds16(asrc1, &As[0][(wave * 2 + 1) * 512]);
  gload_lds16(bsrc0, &Bs[0][(wave * 2 + 0) * 512]);
  gload_lds16(bsrc1, &Bs[0][(wave * 2 + 1) * 512]);
  __syncthreads();

  const int nt = H_ / 32;
  int cur = 0;
  for (int kk = 0; kk < nt; ++kk) {
    if (kk + 1 < nt) {
      const size_t kb = (size_t)(kk + 1) * 64;
      gload_lds16(asrc0 + kb, &As[cur ^ 1][(wave * 2 + 0) * 512]);
      gload_lds16(asrc1 + kb, &As[cur ^ 1][(wave * 2 + 1) * 512]);
      gload_lds16(bsrc0 + kb, &Bs[cur ^ 1][(wave * 2 + 0) * 512]);
      gload_lds16(bsrc1 + kb, &Bs[cur ^ 1][(wave * 2 + 1) * 512]);
    }
    bf16x8 a[4], b[4];
#pragma unroll
    for (int m = 0; m < 4; ++m)
      a[m] = *(const bf16x8*)&As[cur][(wm * 64 + m * 16 + (lane & 15)) * 32 + (lane >> 4) * 8];
#pragma unroll
    for (int g = 0; g < 4; ++g)
      b[g] = *(const bf16x8*)&Bs[cur][((g * 2 + wn) * 16 + (lane & 15)) * 32 + (lane >> 4) * 8];
#pragma unroll
    for (int g = 0; g < 4; ++g)
#pragma unroll
      for (int m = 0; m < 4; ++m)
        acc[g][m] = __builtin_amdgcn_mfma_f32_16x16x32_bf16(a[m], b[g], acc[g][m], 0, 0, 0);
    __syncthreads();
    cur ^= 1;
  }

  const int r0 = (lane >> 4) * 4, cl = lane & 15;
  const int hc = by * 32 + wn * 16 + cl;
#pragma unroll
  for (int m = 0; m < 4; ++m)
#pragma unroll
    for (int j = 0; j < 4; ++j) {
      int row = bx * 128 + wm * 64 + m * 16 + r0 + j;   // batch index
      size_t ci = (size_t)row * H_ + hc;
      u16x4 xv = xg4[ci];
      float iv = sigmf(acc[0][m][j] + bf2f(xv[0]));
      float fv = sigmf(acc[1][m][j] + bf2f(xv[1]));
      float gv = tanh_fast(acc[2][m][j] + bf2f(xv[2]));
      float ov = sigmf(acc[3][m][j] + bf2f(xv[3]));
      float cv = fv * cbuf[ci] + iv * gv;
      cbuf[ci] = cv;
      hout[ci] = f2bf(ov * tanh_fast(cv));
    }
}

// ---------------- batched MLP over NB_ steps ----------------

__global__ __launch_bounds__(256) void k_mlp(
    const unsigned short* __restrict__ hring, const unsigned short* __restrict__ w1,
    const float* __restrict__ b1, const float* __restrict__ w2,
    const float* __restrict__ b2, float* __restrict__ delta, int t0) {
  __shared__ unsigned short As[64 * 32];
  __shared__ unsigned short Bs[64 * 32];
  __shared__ float hid[64][65];
  const int tid = threadIdx.x, lane = tid & 63, wave = tid >> 6;
  const int bx = blockIdx.x;
  const unsigned short* h = hring + (size_t)blockIdx.y * B_ * H_;
  const int t = t0 + blockIdx.y;
  const int r_sub = lane >> 2;
  const int c16 = (lane & 3) * 16;

  f32x4 acc[4];
#pragma unroll
  for (int n = 0; n < 4; ++n) acc[n] = {0.f, 0.f, 0.f, 0.f};

  for (int kk = 0; kk < H_ / 32; ++kk) {
    const int k0 = kk * 32;
    __syncthreads();
    {
      int row = bx * 64 + wave * 16 + r_sub;
      gload_lds16((const char*)h + ((size_t)row * H_ + k0) * 2 + c16,
                  (char*)As + wave * 1024);
    }
    {
      int jj = wave * 16 + r_sub;
      gload_lds16((const char*)w1 + ((size_t)jj * H_ + k0) * 2 + c16,
                  (char*)Bs + wave * 1024);
    }
    __syncthreads();
    bf16x8 a = *(const bf16x8*)&As[(wave * 16 + (lane & 15)) * 32 + (lane >> 4) * 8];
#pragma unroll
    for (int n = 0; n < 4; ++n) {
      bf16x8 b = *(const bf16x8*)&Bs[(n * 16 + (lane & 15)) * 32 + (lane >> 4) * 8];
      acc[n] = __builtin_amdgcn_mfma_f32_16x16x32_bf16(a, b, acc[n], 0, 0, 0);
    }
  }

  const int r0 = (lane >> 4) * 4, cl = lane & 15;
#pragma unroll
  for (int n = 0; n < 4; ++n)
#pragma unroll
    for (int j = 0; j < 4; ++j) {
      int row = wave * 16 + r0 + j;     // local row 0..63
      int col = n * 16 + cl;            // hidden unit 0..63
      hid[row][col] = fmaxf(acc[n][j] + b1[col], 0.0f);
    }
  __syncthreads();

  if (tid < 128) {
    int r = tid >> 1, d = tid & 1;
    float s = b2[d];
#pragma unroll 8
    for (int k2 = 0; k2 < 64; ++k2) s += hid[r][k2] * w2[d * 64 + k2];
    delta[((size_t)(bx * 64 + r) * T_ + t) * 2 + d] = s;
  }
}

// ---------------- final cumsum over T + last_pos ----------------

__global__ void k_cumsum(const float* __restrict__ delta,
                         const float* __restrict__ lp, float* __restrict__ out) {
  int id = blockIdx.x * blockDim.x + threadIdx.x;
  if (id >= B_ * 2) return;
  int b = id >> 1, d = id & 1;
  float cum = lp[b * 2 + d];
  size_t base = (size_t)b * T_ * 2 + d;
  for (int t = 0; t < T_; ++t) {
    cum += delta[base + t * 2];
    out[base + t * 2] = cum;
  }
}

// ---------------- launch ----------------

extern "C" void kernel_launch(void* const* d_in, const int* in_sizes, int n_in,
                              void* d_out, int out_size, void* d_ws, size_t ws_size,
                              hipStream_t stream) {
  const float* z   = (const float*)d_in[0];
  const float* lv  = (const float*)d_in[1];
  const float* lp  = (const float*)d_in[2];
  const float* Wih = (const float*)d_in[3];
  const float* Whh = (const float*)d_in[4];
  const float* bih = (const float*)d_in[5];
  const float* bhh = (const float*)d_in[6];
  const float* W1  = (const float*)d_in[7];
  const float* b1  = (const float*)d_in[8];
  const float* W2  = (const float*)d_in[9];
  const float* b2  = (const float*)d_in[10];
  float* out = (float*)d_out;

  char* ws = (char*)d_ws;
  size_t off = 0;
  u16x4*          xg4    = (u16x4*)(ws + off);          off += (size_t)B_ * H_ * 8;       // 33554432
  unsigned short* whh_bf = (unsigned short*)(ws + off); off += (size_t)G4_ * H_ * 2;      //  8388608
  unsigned short* wih_bf = (unsigned short*)(ws + off); off += (size_t)G4_ * KA_ * 2;     //  8650752
  unsigned short* zaug   = (unsigned short*)(ws + off); off += (size_t)B_ * KA_ * 2;      //  8650752
  unsigned short* w1_bf  = (unsigned short*)(ws + off); off += (size_t)MLPH_ * H_ * 2;    //   131072
  unsigned short* hring  = (unsigned short*)(ws + off); off += (size_t)NB_ * B_ * H_ * 2; // 50331648
  float*          cbuf   = (float*)(ws + off);          off += (size_t)B_ * H_ * 4;       // 16777216
  float*          delta  = (float*)(ws + off);          off += (size_t)B_ * T_ * 2 * 4;   //  1966080
  // total 128450560 bytes

  const size_t BH = (size_t)B_ * H_;

  // zero c and the h(-1) slot (= slot NB_-1 of the ring)
  hipMemsetAsync(hring + (NB_ - 1) * BH, 0, BH * 2, stream);
  hipMemsetAsync(cbuf, 0, BH * 4, stream);

  k_conv_bf16 <<<2048, 256, 0, stream>>>(Whh, whh_bf, G4_ * H_);
  k_conv_wih  <<<2048, 256, 0, stream>>>(Wih, wih_bf);
  k_build_zaug<<<2048, 256, 0, stream>>>(z, lp, lv, zaug);
  k_conv_bf16 <<<256, 256, 0, stream>>>(W1, w1_bf, MLPH_ * H_);

  k_xgates<<<dim3(32, 32), 256, 0, stream>>>(zaug, wih_bf, bih, bhh, xg4);

  for (int t = 0; t < T_; ++t) {
    const unsigned short* hp = hring + (size_t)((t + NB_ - 1) % NB_) * BH;
    unsigned short*       hc = hring + (size_t)(t % NB_) * BH;
    k_step<<<dim3(32, 32), 256, 0, stream>>>(hp, whh_bf, xg4, cbuf, hc);
    if ((t % NB_) == NB_ - 1)
      k_mlp<<<dim3(64, NB_), 256, 0, stream>>>(hring, w1_bf, b1, W2, b2, delta, t - (NB_ - 1));
  }

  k_cumsum<<<32, 256, 0, stream>>>(delta, lp, out);
}